// Round 1
// baseline (391.151 us; speedup 1.0000x reference)
//
#include <hip/hip_runtime.h>
#include <math.h>

#define B_TOTAL 2048
#define T_LEN   512
#define IN_D    6
#define HID     64
#define LAT     16
#define ROWS    2          // batch rows per block -> M-tile rows {0,4}: valid C rows for quads 0,1
#define THREADS 256        // 4 waves; wave w owns output units j in [16w,16w+16) for all 3 gates
#define ASTRIDE 104        // A row stride in bf16 elems (208B = 13x16B aligned)

typedef __attribute__((ext_vector_type(8))) short bfrag;   // 8 bf16 = 4 VGPRs
typedef __attribute__((ext_vector_type(4))) float ffrag;   // 4 fp32 acc

#if __has_builtin(__builtin_amdgcn_exp2f)
#define EXP2F(x) __builtin_amdgcn_exp2f(x)
#else
#define EXP2F(x) exp2f(x)
#endif
#if __has_builtin(__builtin_amdgcn_rcpf)
#define RCPF(x) __builtin_amdgcn_rcpf(x)
#else
#define RCPF(x) (1.0f / (x))
#endif
#define MFMA16(A, B, C) __builtin_amdgcn_mfma_f32_16x16x32_bf16((A), (B), (C), 0, 0, 0)

__device__ __forceinline__ float fast_sigmoid(float x){
    return RCPF(1.0f + EXP2F(-1.44269504088896340736f * x));
}
__device__ __forceinline__ float fast_tanh(float x){
    return 1.0f - 2.0f * RCPF(EXP2F(2.88539008177792681472f * x) + 1.0f);
}
// single-instruction bf16 round-to-nearest-even (replaces 4-op software RNE)
__device__ __forceinline__ unsigned short f2bf_cvt(float f){
    unsigned r;
    asm("v_cvt_pk_bf16_f32 %0, %1, %1" : "=v"(r) : "v"(f));
    return (unsigned short)r;
}

extern "C" __global__ void
__attribute__((amdgpu_flat_work_group_size(THREADS, THREADS), amdgpu_waves_per_eu(4, 4)))
glsde_kernel(const float* __restrict__ x,
             const float* __restrict__ eWih, const float* __restrict__ eWhh,
             const float* __restrict__ ebih, const float* __restrict__ ebhh,
             const float* __restrict__ muW,  const float* __restrict__ mub,
             const float* __restrict__ lvW,  const float* __restrict__ lvb,
             const float* __restrict__ oW,   const float* __restrict__ ob,
             const float* __restrict__ dfW,  const float* __restrict__ dfb,
             const float* __restrict__ dWih, const float* __restrict__ dWhh,
             const float* __restrict__ dbih, const float* __restrict__ dbhh,
             float* __restrict__ out)
{
    // Whole x slice for this block, bf16, pre-formatted as kt=2 A-fragments:
    // xstage[t][b][0..5] = x(b, t, d), [6..7] = 0.  16 KB (ROWS=2).
    __shared__ __align__(16) unsigned short xstage[T_LEN][ROWS][8];
    __shared__ __align__(16) unsigned short Abuf[2][16][ASTRIDE];  // [buf][m][k] bf16 (h part)
    __shared__ float hfp[ROWS][HID];
    __shared__ float zsh[ROWS][LAT];
    __shared__ float zdsh[ROWS][HID];
    __shared__ float xgdsh[ROWS][3];

    const int tid  = threadIdx.x;
    const int wave = tid >> 6;
    const int lane = tid & 63;
    const int nloc = lane & 15;
    const int quad = lane >> 4;
    const int mA   = lane & 15;
    const int j    = wave * 16 + nloc;   // output unit 0..63
    const int b0   = blockIdx.x * ROWS;

    const float S1 = 1.44269504088896340736f;  // log2(e): sigmoid via exp2
    const float S2 = 2.0f * S1;                // tanh via exp2(2x)

    // ---- weights (pre-scaled by S1/S2) -> registers, plain bf16, loaded ONCE ----
    bfrag Br[3], Bz[3], Bnh[2], Bnx;
    {
        const float* wr  = eWhh + (size_t)(      j) * HID;
        const float* wz  = eWhh + (size_t)( 64 + j) * HID;
        const float* wn  = eWhh + (size_t)(128 + j) * HID;
        #pragma unroll
        for (int kt = 0; kt < 2; ++kt){
            const int o = kt * 32 + quad * 8;
            #pragma unroll
            for (int e = 0; e < 8; ++e){
                Br[kt][e]  = (short)f2bf_cvt(wr[o+e] * S1);
                Bz[kt][e]  = (short)f2bf_cvt(wz[o+e] * S1);
                Bnh[kt][e] = (short)f2bf_cvt(wn[o+e] * S2);
            }
        }
        const float* ir  = eWih + (size_t)(      j) * IN_D;
        const float* iz  = eWih + (size_t)( 64 + j) * IN_D;
        const float* inn = eWih + (size_t)(128 + j) * IN_D;
        #pragma unroll
        for (int e = 0; e < 8; ++e){
            bool v = (quad == 0 && e < IN_D);
            Br[2][e] = v ? (short)f2bf_cvt(ir[e]  * S1) : (short)0;
            Bz[2][e] = v ? (short)f2bf_cvt(iz[e]  * S1) : (short)0;
            Bnx[e]   = v ? (short)f2bf_cvt(inn[e] * S2) : (short)0;
        }
    }
    const float bias_r = (ebih[j]      + ebhh[j])      * S1;
    const float bias_z = (ebih[64 + j] + ebhh[64 + j]) * S1;
    const float bihn2  = ebih[128 + j] * S2;
    const float bhhn2  = ebhh[128 + j] * S2;

    // ---- zero Abuf (h(0)=0; rows not written stay 0 forever) ----
    {
        unsigned* ap = (unsigned*)Abuf;
        for (int i = tid; i < (int)(sizeof(Abuf) / 4); i += THREADS) ap[i] = 0u;
    }

    // ---- stage ALL of x for this block into LDS (one-time) ----
    for (int idx = tid; idx < T_LEN * ROWS; idx += THREADS){
        const int tt = idx & (T_LEN - 1);
        const int bb = idx >> 9;
        const float* xr = x + (size_t)(b0 + bb) * T_LEN * IN_D + (size_t)tt * IN_D;
        const float2* p2 = (const float2*)xr;           // 8B-aligned (24B stride)
        float2 v0 = p2[0], v1 = p2[1], v2 = p2[2];
        bfrag f;
        f[0] = (short)f2bf_cvt(v0.x); f[1] = (short)f2bf_cvt(v0.y);
        f[2] = (short)f2bf_cvt(v1.x); f[3] = (short)f2bf_cvt(v1.y);
        f[4] = (short)f2bf_cvt(v2.x); f[5] = (short)f2bf_cvt(v2.y);
        f[6] = 0; f[7] = 0;
        *(bfrag*)&xstage[tt][bb][0] = f;
    }
    __syncthreads();

    // lane (quad, j) owns batch row quad (M row quad*4, valid for quad < ROWS)
    float hreg = 0.f;

    // x A-fragment source: A row mA maps to batch row (mA>>2) & (ROWS-1)
    // (garbage-but-bounded for invalid M rows; C row r depends only on A row r)
    const unsigned short* xsp = &xstage[0][(mA >> 2) & (ROWS - 1)][0];

    // Ax register pipeline: Ax holds fragment for step t; AxN prefetches t+1.
    bfrag Ax = *(const bfrag*)(xsp);

#define GRU_STEP(bufR, bufW, T)                                                   \
    do {                                                                          \
        const unsigned short* ah_ = &bufR[mA][0];                                 \
        bfrag Ah0 = *(const bfrag*)(ah_ + 0  + quad * 8);                         \
        bfrag Ah1 = *(const bfrag*)(ah_ + 32 + quad * 8);                         \
        const int tn_ = ((T) + 1) & (T_LEN - 1);                                  \
        bfrag AxN = *(const bfrag*)(xsp + (size_t)tn_ * (ROWS * 8));              \
        ffrag aR  = {bias_r, bias_r, bias_r, bias_r};                             \
        ffrag aZ  = {bias_z, bias_z, bias_z, bias_z};                             \
        ffrag aNX = {bihn2,  bihn2,  bihn2,  bihn2 };                             \
        ffrag aNH = {bhhn2,  bhhn2,  bhhn2,  bhhn2 };                             \
        /* x-part first: Ax resident, overlaps Ah ds_read latency */              \
        aR  = MFMA16(Ax,  Br[2],  aR );                                           \
        aZ  = MFMA16(Ax,  Bz[2],  aZ );                                           \
        aNX = MFMA16(Ax,  Bnx,    aNX);                                           \
        aR  = MFMA16(Ah0, Br[0],  aR );                                           \
        aZ  = MFMA16(Ah0, Bz[0],  aZ );                                           \
        aNH = MFMA16(Ah0, Bnh[0], aNH);                                           \
        aR  = MFMA16(Ah1, Br[1],  aR );                                           \
        aZ  = MFMA16(Ah1, Bz[1],  aZ );                                           \
        aNH = MFMA16(Ah1, Bnh[1], aNH);                                           \
        float rg = RCPF(1.0f + EXP2F(-aR[0]));                                    \
        float zg = RCPF(1.0f + EXP2F(-aZ[0]));                                    \
        float yy = aNX[0] + rg * aNH[0];                                          \
        float ng = 1.0f - 2.0f * RCPF(EXP2F(yy) + 1.0f);                          \
        float hn = (1.0f - zg) * ng + zg * hreg;                                  \
        hreg = hn;                                                                \
        bufW[quad * 4][j] = f2bf_cvt(hn);                                         \
        Ax = AxN;                                                                 \
        __syncthreads();                                                          \
    } while (0)

    // ================= encoder GRU: 512 steps, 1 barrier/step, NO global ops =====
    for (int t = 0; t < T_LEN; t += 2){
        GRU_STEP(Abuf[0], Abuf[1], t);
        GRU_STEP(Abuf[1], Abuf[0], t + 1);
    }
#undef GRU_STEP

    // ---- publish final h (fp32, from registers): batch row = quad ----
    if (quad < ROWS) hfp[quad][j] = hreg;
    __syncthreads();

    // ================= heads: mu, logvar, z0 =================
    const int zrow = tid >> 4, zi = tid & 15;
    float z0v = 0.0f;
    if (tid < ROWS * LAT){
        float am = mub[zi], al = lvb[zi];
        const float4* pm = (const float4*)(muW + (size_t)zi * HID);
        const float4* pq = (const float4*)(lvW + (size_t)zi * HID);
        const float4* ph = (const float4*)(&hfp[zrow][0]);
        #pragma unroll
        for (int q = 0; q < 16; ++q){
            float4 wm = pm[q], wl = pq[q], hv = ph[q];
            am += wm.x*hv.x + wm.y*hv.y + wm.z*hv.z + wm.w*hv.w;
            al += wl.x*hv.x + wl.y*hv.y + wl.z*hv.z + wl.w*hv.w;
        }
        const size_t muBase = (size_t)B_TOTAL * T_LEN;
        out[muBase + (size_t)(b0 + zrow) * LAT + zi] = am;
        out[muBase + (size_t)B_TOTAL * LAT + (size_t)(b0 + zrow) * LAT + zi] = al;
        z0v = am + __expf(0.5f * al);
    }

    // ================= ODE: RK4, 24 fixed steps on [0,1] =================
    if (tid < ROWS * LAT){
        float ows[16];
        {
            const float4* pw = (const float4*)(oW + (size_t)zi * LAT);
            #pragma unroll
            for (int q = 0; q < 4; ++q){
                float4 w = pw[q];
                ows[4*q+0] = w.x; ows[4*q+1] = w.y; ows[4*q+2] = w.z; ows[4*q+3] = w.w;
            }
        }
        const float obv = ob[zi];
        float z = z0v;
        const float hstep = 1.0f / 24.0f;
        for (int s = 0; s < 24; ++s){
            float y, k1, k2, k3, k4;
            y = z;
            { float acc = obv;
              #pragma unroll
              for (int jj = 0; jj < 16; ++jj){ float yj = __shfl(y, jj, 16); acc = fmaf(ows[jj], yj, acc); }
              k1 = fmaxf(acc, 0.0f); }
            y = z + 0.5f * hstep * k1;
            { float acc = obv;
              #pragma unroll
              for (int jj = 0; jj < 16; ++jj){ float yj = __shfl(y, jj, 16); acc = fmaf(ows[jj], yj, acc); }
              k2 = fmaxf(acc, 0.0f); }
            y = z + 0.5f * hstep * k2;
            { float acc = obv;
              #pragma unroll
              for (int jj = 0; jj < 16; ++jj){ float yj = __shfl(y, jj, 16); acc = fmaf(ows[jj], yj, acc); }
              k3 = fmaxf(acc, 0.0f); }
            y = z + hstep * k3;
            { float acc = obv;
              #pragma unroll
              for (int jj = 0; jj < 16; ++jj){ float yj = __shfl(y, jj, 16); acc = fmaf(ows[jj], yj, acc); }
              k4 = fmaxf(acc, 0.0f); }
            z += (hstep / 6.0f) * (k1 + 2.0f*k2 + 2.0f*k3 + k4);
        }
        zsh[zrow][zi] = z;
    }
    __syncthreads();

    // ================= decoder fc: zd = relu(z @ dfW.T + dfb) =================
    for (int idx = tid; idx < ROWS * HID; idx += THREADS){
        const int row = idx >> 6, o = idx & 63;
        float acc = dfb[o];
        const float4* pw = (const float4*)(dfW + (size_t)o * LAT);
        const float4* pz = (const float4*)(&zsh[row][0]);
        #pragma unroll
        for (int q = 0; q < 4; ++q){
            float4 w = pw[q], zv = pz[q];
            acc += w.x*zv.x + w.y*zv.y + w.z*zv.z + w.w*zv.w;
        }
        zdsh[row][o] = fmaxf(acc, 0.0f);
    }
    __syncthreads();

    // xg_dec = zd @ dec_Wih.T + dec_bih
    if (tid < ROWS * 3){
        const int row = tid / 3, gg = tid % 3;
        float acc = dbih[gg];
        const float4* pw = (const float4*)(dWih + (size_t)gg * HID);
        const float4* pz = (const float4*)(&zdsh[row][0]);
        #pragma unroll
        for (int q = 0; q < 16; ++q){
            float4 w = pw[q], zv = pz[q];
            acc += w.x*zv.x + w.y*zv.y + w.z*zv.z + w.w*zv.w;
        }
        xgdsh[row][gg] = acc;
    }
    __syncthreads();

    // ====== decoder GRU (hidden dim 1), 512 steps, direct float4 global stores ===
    if (tid < ROWS){
        const int row = tid;
        const float xr = xgdsh[row][0], xz = xgdsh[row][1], xn = xgdsh[row][2];
        const float A0 = dWhh[0], A1 = dWhh[1], A2 = dWhh[2];
        const float c0 = dbhh[0], c1 = dbhh[1], c2 = dbhh[2];
        float* orow = out + (size_t)(b0 + row) * T_LEN;   // 16B-aligned
        float h = 0.0f;
        float ob4[4];
        for (int t = 0; t < T_LEN; ++t){
            float rr = fast_sigmoid(xr + A0 * h + c0);
            float zz = fast_sigmoid(xz + A1 * h + c1);
            float nn = fast_tanh(xn + rr * (A2 * h + c2));
            h = (1.0f - zz) * nn + zz * h;
            ob4[t & 3] = h;
            if ((t & 3) == 3) *(float4*)(orow + (t - 3)) = *(float4*)ob4;
        }
    }
}

extern "C" void kernel_launch(void* const* d_in, const int* in_sizes, int n_in,
                              void* d_out, int out_size, void* d_ws, size_t ws_size,
                              hipStream_t stream){
    glsde_kernel<<<B_TOTAL / ROWS, THREADS, 0, stream>>>(
        (const float*)d_in[0],  (const float*)d_in[1],  (const float*)d_in[2],
        (const float*)d_in[3],  (const float*)d_in[4],  (const float*)d_in[5],
        (const float*)d_in[6],  (const float*)d_in[7],  (const float*)d_in[8],
        (const float*)d_in[9],  (const float*)d_in[10], (const float*)d_in[11],
        (const float*)d_in[12], (const float*)d_in[13], (const float*)d_in[14],
        (const float*)d_in[15], (const float*)d_in[16], (float*)d_out);
}

// Round 2
// 346.502 us; speedup vs baseline: 1.1289x; 1.1289x over previous
//
#include <hip/hip_runtime.h>
#include <math.h>

#define B_TOTAL 2048
#define T_LEN   512
#define IN_D    6
#define HID     64
#define LAT     16
#define ROWS    8          // batch rows per block -> M rows 0..7 of the 16x16 MFMA
#define THREADS 256        // 4 waves; wave w owns output units j in [16w,16w+16) for all 3 gates
#define ASTRIDE 104        // A row stride in bf16 elems (208B = 13x16B aligned)

typedef __attribute__((ext_vector_type(8))) short bfrag;   // 8 bf16 = 4 VGPRs
typedef __attribute__((ext_vector_type(4))) float ffrag;   // 4 fp32 acc
typedef union { bfrag f; unsigned u[4]; } bfu;

#if __has_builtin(__builtin_amdgcn_exp2f)
#define EXP2F(x) __builtin_amdgcn_exp2f(x)
#else
#define EXP2F(x) exp2f(x)
#endif
#if __has_builtin(__builtin_amdgcn_rcpf)
#define RCPF(x) __builtin_amdgcn_rcpf(x)
#else
#define RCPF(x) (1.0f / (x))
#endif
#define MFMA16(A, B, C) __builtin_amdgcn_mfma_f32_16x16x32_bf16((A), (B), (C), 0, 0, 0)

__device__ __forceinline__ float fast_sigmoid(float x){
    return RCPF(1.0f + EXP2F(-1.44269504088896340736f * x));
}
__device__ __forceinline__ float fast_tanh(float x){
    return 1.0f - 2.0f * RCPF(EXP2F(2.88539008177792681472f * x) + 1.0f);
}
// single-instruction bf16 round-to-nearest-even
__device__ __forceinline__ unsigned short f2bf_cvt(float f){
    unsigned r;
    asm("v_cvt_pk_bf16_f32 %0, %1, %1" : "=v"(r) : "v"(f));
    return (unsigned short)r;
}
// pack two f32 -> two bf16 in one dword (lo in [15:0], hi in [31:16])
__device__ __forceinline__ unsigned f2bf_pk(float lo, float hi){
    unsigned r;
    asm("v_cvt_pk_bf16_f32 %0, %1, %2" : "=v"(r) : "v"(lo), "v"(hi));
    return r;
}

extern "C" __global__ void
__attribute__((amdgpu_flat_work_group_size(THREADS, THREADS)))
glsde_kernel(const float* __restrict__ x,
             const float* __restrict__ eWih, const float* __restrict__ eWhh,
             const float* __restrict__ ebih, const float* __restrict__ ebhh,
             const float* __restrict__ muW,  const float* __restrict__ mub,
             const float* __restrict__ lvW,  const float* __restrict__ lvb,
             const float* __restrict__ oW,   const float* __restrict__ ob,
             const float* __restrict__ dfW,  const float* __restrict__ dfb,
             const float* __restrict__ dWih, const float* __restrict__ dWhh,
             const float* __restrict__ dbih, const float* __restrict__ dbhh,
             float* __restrict__ out)
{
    // x for this block, bf16, packed 6 shorts per (t,row): 48 KB.
    __shared__ __align__(16) unsigned short xstage[T_LEN][ROWS][6];
    __shared__ __align__(16) unsigned short Abuf[2][16][ASTRIDE];  // [buf][m][k] bf16 (h part)
    __shared__ float hfp[ROWS][HID];
    __shared__ float zsh[ROWS][LAT];
    __shared__ float zdsh[ROWS][HID];
    __shared__ float xgdsh[ROWS][3];

    const int tid  = threadIdx.x;
    const int wave = tid >> 6;
    const int lane = tid & 63;
    const int nloc = lane & 15;
    const int quad = lane >> 4;
    const int mA   = lane & 15;
    const int j    = wave * 16 + nloc;   // output unit 0..63
    const int b0   = blockIdx.x * ROWS;

    const float S1 = 1.44269504088896340736f;  // log2(e): sigmoid via exp2
    const float S2 = 2.0f * S1;                // tanh via exp2(2x)

    // ---- weights (pre-scaled by S1/S2) -> registers, plain bf16, loaded ONCE ----
    bfrag Br[3], Bz[3], Bnh[2], Bnx;
    {
        const float* wr  = eWhh + (size_t)(      j) * HID;
        const float* wz  = eWhh + (size_t)( 64 + j) * HID;
        const float* wn  = eWhh + (size_t)(128 + j) * HID;
        #pragma unroll
        for (int kt = 0; kt < 2; ++kt){
            const int o = kt * 32 + quad * 8;
            #pragma unroll
            for (int e = 0; e < 8; ++e){
                Br[kt][e]  = (short)f2bf_cvt(wr[o+e] * S1);
                Bz[kt][e]  = (short)f2bf_cvt(wz[o+e] * S1);
                Bnh[kt][e] = (short)f2bf_cvt(wn[o+e] * S2);
            }
        }
        const float* ir  = eWih + (size_t)(      j) * IN_D;
        const float* iz  = eWih + (size_t)( 64 + j) * IN_D;
        const float* inn = eWih + (size_t)(128 + j) * IN_D;
        #pragma unroll
        for (int e = 0; e < 8; ++e){
            bool v = (quad == 0 && e < IN_D);
            Br[2][e] = v ? (short)f2bf_cvt(ir[e]  * S1) : (short)0;
            Bz[2][e] = v ? (short)f2bf_cvt(iz[e]  * S1) : (short)0;
            Bnx[e]   = v ? (short)f2bf_cvt(inn[e] * S2) : (short)0;
        }
    }
    const float bias_r = (ebih[j]      + ebhh[j])      * S1;
    const float bias_z = (ebih[64 + j] + ebhh[64 + j]) * S1;
    const float bihn2  = ebih[128 + j] * S2;
    const float bhhn2  = ebhh[128 + j] * S2;

    // ---- zero Abuf (h(0)=0; M rows 8..15 stay 0 forever) ----
    {
        unsigned* ap = (unsigned*)Abuf;
        for (int i = tid; i < (int)(sizeof(Abuf) / 4); i += THREADS) ap[i] = 0u;
    }

    // ---- stage ALL of x for this block into LDS (one-time), bf16-packed ----
    for (int idx = tid; idx < T_LEN * ROWS; idx += THREADS){
        const int tt = idx & (T_LEN - 1);
        const int bb = idx >> 9;
        const float* xr = x + (size_t)(b0 + bb) * T_LEN * IN_D + (size_t)tt * IN_D;
        const float2* p2 = (const float2*)xr;           // 8B-aligned (24B stride)
        float2 v0 = p2[0], v1 = p2[1], v2 = p2[2];
        unsigned* dst = (unsigned*)&xstage[tt][bb][0];  // 12B-aligned -> dword ok
        dst[0] = f2bf_pk(v0.x, v0.y);
        dst[1] = f2bf_pk(v1.x, v1.y);
        dst[2] = f2bf_pk(v2.x, v2.y);
    }
    __syncthreads();

    // lane (quad<2, reg r) owns batch row quad*4+r; h state in registers
    float hreg[4] = {0.f, 0.f, 0.f, 0.f};

    // x A-fragment source: M row mA = batch row mA (mA>=8 duplicates mA&7, harmless:
    // B-side x fragments are zero for quad>0 / e>=IN_D, and C rows 8..15 unused)
    const unsigned short* xsp = &xstage[0][mA & (ROWS - 1)][0];

    // Ax register pipeline: Ax holds fragment for step t; AxN prefetches t+1.
    bfu Ax;
    {
        const unsigned* xp = (const unsigned*)xsp;
        Ax.u[0] = xp[0]; Ax.u[1] = xp[1]; Ax.u[2] = xp[2]; Ax.u[3] = 0u;
    }

    auto gru_step = [&](const unsigned short (*bufR)[ASTRIDE],
                        unsigned short (*bufW)[ASTRIDE], int T){
        const unsigned short* ah_ = &bufR[mA][0];
        bfrag Ah0 = *(const bfrag*)(ah_ + 0  + quad * 8);
        bfrag Ah1 = *(const bfrag*)(ah_ + 32 + quad * 8);
        const int tn_ = (T + 1) & (T_LEN - 1);
        const unsigned* xpn = (const unsigned*)(xsp + (size_t)tn_ * (ROWS * 6));
        bfu AxN;
        AxN.u[0] = xpn[0]; AxN.u[1] = xpn[1]; AxN.u[2] = xpn[2]; AxN.u[3] = 0u;
        ffrag aR  = {bias_r, bias_r, bias_r, bias_r};
        ffrag aZ  = {bias_z, bias_z, bias_z, bias_z};
        ffrag aNX = {bihn2,  bihn2,  bihn2,  bihn2 };
        ffrag aNH = {bhhn2,  bhhn2,  bhhn2,  bhhn2 };
        // x-part first: Ax resident, overlaps Ah ds_read latency
        aR  = MFMA16(Ax.f, Br[2],  aR );
        aZ  = MFMA16(Ax.f, Bz[2],  aZ );
        aNX = MFMA16(Ax.f, Bnx,    aNX);
        aR  = MFMA16(Ah0,  Br[0],  aR );
        aZ  = MFMA16(Ah0,  Bz[0],  aZ );
        aNH = MFMA16(Ah0,  Bnh[0], aNH);
        aR  = MFMA16(Ah1,  Br[1],  aR );
        aZ  = MFMA16(Ah1,  Bz[1],  aZ );
        aNH = MFMA16(Ah1,  Bnh[1], aNH);
        if (quad < 2){
            #pragma unroll
            for (int r_ = 0; r_ < 4; ++r_){
                float rg = RCPF(1.0f + EXP2F(-aR[r_]));
                float zg = RCPF(1.0f + EXP2F(-aZ[r_]));
                float yy = aNX[r_] + rg * aNH[r_];
                float ng = 1.0f - 2.0f * RCPF(EXP2F(yy) + 1.0f);
                float hn = (1.0f - zg) * ng + zg * hreg[r_];
                hreg[r_] = hn;
                bufW[quad * 4 + r_][j] = f2bf_cvt(hn);
            }
        }
        Ax = AxN;
        __syncthreads();
    };

    // ================= encoder GRU: 512 steps, 1 barrier/step, NO global ops =====
    for (int t = 0; t < T_LEN; t += 2){
        gru_step(Abuf[0], Abuf[1], t);
        gru_step(Abuf[1], Abuf[0], t + 1);
    }

    // ---- publish final h (fp32, from registers): batch row = quad*4+r ----
    if (quad < 2){
        #pragma unroll
        for (int r_ = 0; r_ < 4; ++r_) hfp[quad * 4 + r_][j] = hreg[r_];
    }
    __syncthreads();

    // ================= heads: mu, logvar, z0 =================
    const int zrow = tid >> 4, zi = tid & 15;
    float z0v = 0.0f;
    if (tid < ROWS * LAT){
        float am = mub[zi], al = lvb[zi];
        const float4* pm = (const float4*)(muW + (size_t)zi * HID);
        const float4* pq = (const float4*)(lvW + (size_t)zi * HID);
        const float4* ph = (const float4*)(&hfp[zrow][0]);
        #pragma unroll
        for (int q = 0; q < 16; ++q){
            float4 wm = pm[q], wl = pq[q], hv = ph[q];
            am += wm.x*hv.x + wm.y*hv.y + wm.z*hv.z + wm.w*hv.w;
            al += wl.x*hv.x + wl.y*hv.y + wl.z*hv.z + wl.w*hv.w;
        }
        const size_t muBase = (size_t)B_TOTAL * T_LEN;
        out[muBase + (size_t)(b0 + zrow) * LAT + zi] = am;
        out[muBase + (size_t)B_TOTAL * LAT + (size_t)(b0 + zrow) * LAT + zi] = al;
        z0v = am + __expf(0.5f * al);
    }

    // ================= ODE: RK4, 24 fixed steps on [0,1] =================
    if (tid < ROWS * LAT){
        float ows[16];
        {
            const float4* pw = (const float4*)(oW + (size_t)zi * LAT);
            #pragma unroll
            for (int q = 0; q < 4; ++q){
                float4 w = pw[q];
                ows[4*q+0] = w.x; ows[4*q+1] = w.y; ows[4*q+2] = w.z; ows[4*q+3] = w.w;
            }
        }
        const float obv = ob[zi];
        float z = z0v;
        const float hstep = 1.0f / 24.0f;
        for (int s = 0; s < 24; ++s){
            float y, k1, k2, k3, k4;
            y = z;
            { float acc = obv;
              #pragma unroll
              for (int jj = 0; jj < 16; ++jj){ float yj = __shfl(y, jj, 16); acc = fmaf(ows[jj], yj, acc); }
              k1 = fmaxf(acc, 0.0f); }
            y = z + 0.5f * hstep * k1;
            { float acc = obv;
              #pragma unroll
              for (int jj = 0; jj < 16; ++jj){ float yj = __shfl(y, jj, 16); acc = fmaf(ows[jj], yj, acc); }
              k2 = fmaxf(acc, 0.0f); }
            y = z + 0.5f * hstep * k2;
            { float acc = obv;
              #pragma unroll
              for (int jj = 0; jj < 16; ++jj){ float yj = __shfl(y, jj, 16); acc = fmaf(ows[jj], yj, acc); }
              k3 = fmaxf(acc, 0.0f); }
            y = z + hstep * k3;
            { float acc = obv;
              #pragma unroll
              for (int jj = 0; jj < 16; ++jj){ float yj = __shfl(y, jj, 16); acc = fmaf(ows[jj], yj, acc); }
              k4 = fmaxf(acc, 0.0f); }
            z += (hstep / 6.0f) * (k1 + 2.0f*k2 + 2.0f*k3 + k4);
        }
        zsh[zrow][zi] = z;
    }
    __syncthreads();

    // ================= decoder fc: zd = relu(z @ dfW.T + dfb) =================
    for (int idx = tid; idx < ROWS * HID; idx += THREADS){
        const int row = idx >> 6, o = idx & 63;
        float acc = dfb[o];
        const float4* pw = (const float4*)(dfW + (size_t)o * LAT);
        const float4* pz = (const float4*)(&zsh[row][0]);
        #pragma unroll
        for (int q = 0; q < 4; ++q){
            float4 w = pw[q], zv = pz[q];
            acc += w.x*zv.x + w.y*zv.y + w.z*zv.z + w.w*zv.w;
        }
        zdsh[row][o] = fmaxf(acc, 0.0f);
    }
    __syncthreads();

    // xg_dec = zd @ dec_Wih.T + dec_bih
    if (tid < ROWS * 3){
        const int row = tid / 3, gg = tid % 3;
        float acc = dbih[gg];
        const float4* pw = (const float4*)(dWih + (size_t)gg * HID);
        const float4* pz = (const float4*)(&zdsh[row][0]);
        #pragma unroll
        for (int q = 0; q < 16; ++q){
            float4 w = pw[q], zv = pz[q];
            acc += w.x*zv.x + w.y*zv.y + w.z*zv.z + w.w*zv.w;
        }
        xgdsh[row][gg] = acc;
    }
    __syncthreads();

    // ====== decoder GRU (hidden dim 1), 512 steps, direct float4 global stores ===
    if (tid < ROWS){
        const int row = tid;
        const float xr = xgdsh[row][0], xz = xgdsh[row][1], xn = xgdsh[row][2];
        const float A0 = dWhh[0], A1 = dWhh[1], A2 = dWhh[2];
        const float c0 = dbhh[0], c1 = dbhh[1], c2 = dbhh[2];
        float* orow = out + (size_t)(b0 + row) * T_LEN;   // 16B-aligned
        float h = 0.0f;
        float ob4[4];
        for (int t = 0; t < T_LEN; ++t){
            float rr = fast_sigmoid(xr + A0 * h + c0);
            float zz = fast_sigmoid(xz + A1 * h + c1);
            float nn = fast_tanh(xn + rr * (A2 * h + c2));
            h = (1.0f - zz) * nn + zz * h;
            ob4[t & 3] = h;
            if ((t & 3) == 3) *(float4*)(orow + (t - 3)) = *(float4*)ob4;
        }
    }
}

extern "C" void kernel_launch(void* const* d_in, const int* in_sizes, int n_in,
                              void* d_out, int out_size, void* d_ws, size_t ws_size,
                              hipStream_t stream){
    glsde_kernel<<<B_TOTAL / ROWS, THREADS, 0, stream>>>(
        (const float*)d_in[0],  (const float*)d_in[1],  (const float*)d_in[2],
        (const float*)d_in[3],  (const float*)d_in[4],  (const float*)d_in[5],
        (const float*)d_in[6],  (const float*)d_in[7],  (const float*)d_in[8],
        (const float*)d_in[9],  (const float*)d_in[10], (const float*)d_in[11],
        (const float*)d_in[12], (const float*)d_in[13], (const float*)d_in[14],
        (const float*)d_in[15], (const float*)d_in[16], (float*)d_out);
}

// Round 3
// 320.860 us; speedup vs baseline: 1.2191x; 1.0799x over previous
//
#include <hip/hip_runtime.h>
#include <math.h>

#define B_TOTAL 2048
#define T_LEN   512
#define IN_D    6
#define HID     64
#define LAT     16
#define ROWS    8          // batch rows per block; M rows {0,1,4,5,8,9,12,13}: quad q regs 0..1 = rows 2q,2q+1
#define THREADS 256        // 4 waves; wave w owns output units j in [16w,16w+16) for all 3 gates
#define ASTRIDE 104        // A row stride in bf16 elems (208B = 13x16B aligned)

typedef __attribute__((ext_vector_type(8))) short bfrag;   // 8 bf16 = 4 VGPRs
typedef __attribute__((ext_vector_type(4))) float ffrag;   // 4 fp32 acc
typedef union { bfrag f; unsigned u[4]; } bfu;

#if __has_builtin(__builtin_amdgcn_exp2f)
#define EXP2F(x) __builtin_amdgcn_exp2f(x)
#else
#define EXP2F(x) exp2f(x)
#endif
#if __has_builtin(__builtin_amdgcn_rcpf)
#define RCPF(x) __builtin_amdgcn_rcpf(x)
#else
#define RCPF(x) (1.0f / (x))
#endif
#define MFMA16(A, B, C) __builtin_amdgcn_mfma_f32_16x16x32_bf16((A), (B), (C), 0, 0, 0)

__device__ __forceinline__ float fast_sigmoid(float x){
    return RCPF(1.0f + EXP2F(-1.44269504088896340736f * x));
}
__device__ __forceinline__ float fast_tanh(float x){
    return 1.0f - 2.0f * RCPF(EXP2F(2.88539008177792681472f * x) + 1.0f);
}
// single-instruction bf16 round-to-nearest-even
__device__ __forceinline__ unsigned short f2bf_cvt(float f){
    unsigned r;
    asm("v_cvt_pk_bf16_f32 %0, %1, %1" : "=v"(r) : "v"(f));
    return (unsigned short)r;
}
// pack two f32 -> two bf16 in one dword (lo in [15:0], hi in [31:16])
__device__ __forceinline__ unsigned f2bf_pk(float lo, float hi){
    unsigned r;
    asm("v_cvt_pk_bf16_f32 %0, %1, %2" : "=v"(r) : "v"(lo), "v"(hi));
    return r;
}

extern "C" __global__ void
__attribute__((amdgpu_flat_work_group_size(THREADS, THREADS)))
glsde_kernel(const float* __restrict__ x,
             const float* __restrict__ eWih, const float* __restrict__ eWhh,
             const float* __restrict__ ebih, const float* __restrict__ ebhh,
             const float* __restrict__ muW,  const float* __restrict__ mub,
             const float* __restrict__ lvW,  const float* __restrict__ lvb,
             const float* __restrict__ oW,   const float* __restrict__ ob,
             const float* __restrict__ dfW,  const float* __restrict__ dfb,
             const float* __restrict__ dWih, const float* __restrict__ dWhh,
             const float* __restrict__ dbih, const float* __restrict__ dbhh,
             float* __restrict__ out)
{
    // x for this block, bf16, packed 6 shorts per (t,row): 48 KB.
    __shared__ __align__(16) unsigned short xstage[T_LEN][ROWS][6];
    __shared__ __align__(16) unsigned short Abuf[2][16][ASTRIDE];  // [buf][m][k] bf16 (h part)
    __shared__ float hfp[ROWS][HID];
    __shared__ float zsh[ROWS][LAT];
    __shared__ float zdsh[ROWS][HID];
    __shared__ float xgdsh[ROWS][3];

    const int tid  = threadIdx.x;
    const int wave = tid >> 6;
    const int lane = tid & 63;
    const int nloc = lane & 15;
    const int quad = lane >> 4;
    const int mA   = lane & 15;
    const int j    = wave * 16 + nloc;   // output unit 0..63
    const int b0   = blockIdx.x * ROWS;

    const float S1 = 1.44269504088896340736f;  // log2(e): sigmoid via exp2
    const float S2 = 2.0f * S1;                // tanh via exp2(2x)

    // ---- weights (pre-scaled by S1/S2) -> registers, plain bf16, loaded ONCE ----
    bfrag Br[3], Bz[3], Bnh[2], Bnx;
    {
        const float* wr  = eWhh + (size_t)(      j) * HID;
        const float* wz  = eWhh + (size_t)( 64 + j) * HID;
        const float* wn  = eWhh + (size_t)(128 + j) * HID;
        #pragma unroll
        for (int kt = 0; kt < 2; ++kt){
            const int o = kt * 32 + quad * 8;
            #pragma unroll
            for (int e = 0; e < 8; ++e){
                Br[kt][e]  = (short)f2bf_cvt(wr[o+e] * S1);
                Bz[kt][e]  = (short)f2bf_cvt(wz[o+e] * S1);
                Bnh[kt][e] = (short)f2bf_cvt(wn[o+e] * S2);
            }
        }
        const float* ir  = eWih + (size_t)(      j) * IN_D;
        const float* iz  = eWih + (size_t)( 64 + j) * IN_D;
        const float* inn = eWih + (size_t)(128 + j) * IN_D;
        #pragma unroll
        for (int e = 0; e < 8; ++e){
            bool v = (quad == 0 && e < IN_D);
            Br[2][e] = v ? (short)f2bf_cvt(ir[e]  * S1) : (short)0;
            Bz[2][e] = v ? (short)f2bf_cvt(iz[e]  * S1) : (short)0;
            Bnx[e]   = v ? (short)f2bf_cvt(inn[e] * S2) : (short)0;
        }
    }
    const float bias_r = (ebih[j]      + ebhh[j])      * S1;
    const float bias_z = (ebih[64 + j] + ebhh[64 + j]) * S1;
    const float bihn2  = ebih[128 + j] * S2;
    const float bhhn2  = ebhh[128 + j] * S2;

    // hoisted C-input fragments (loop-invariant)
    const ffrag FBR  = {bias_r, bias_r, bias_r, bias_r};
    const ffrag FBZ  = {bias_z, bias_z, bias_z, bias_z};
    const ffrag FBNX = {bihn2,  bihn2,  bihn2,  bihn2 };
    const ffrag FBNH = {bhhn2,  bhhn2,  bhhn2,  bhhn2 };
    const ffrag FZ   = {0.0f, 0.0f, 0.0f, 0.0f};

    // ---- zero Abuf (h(0)=0; M rows 4q+2,4q+3 stay 0 forever) ----
    {
        unsigned* ap = (unsigned*)Abuf;
        for (int i = tid; i < (int)(sizeof(Abuf) / 4); i += THREADS) ap[i] = 0u;
    }

    // ---- stage ALL of x for this block into LDS (one-time), bf16-packed ----
    for (int idx = tid; idx < T_LEN * ROWS; idx += THREADS){
        const int tt = idx & (T_LEN - 1);
        const int bb = idx >> 9;
        const float* xr = x + (size_t)(b0 + bb) * T_LEN * IN_D + (size_t)tt * IN_D;
        const float2* p2 = (const float2*)xr;           // 8B-aligned (24B stride)
        float2 v0 = p2[0], v1 = p2[1], v2 = p2[2];
        unsigned* dst = (unsigned*)&xstage[tt][bb][0];  // 12B-aligned -> dword ok
        dst[0] = f2bf_pk(v0.x, v0.y);
        dst[1] = f2bf_pk(v1.x, v1.y);
        dst[2] = f2bf_pk(v2.x, v2.y);
    }
    __syncthreads();

    // lane (quad, reg r<2) owns batch row 2*quad+r; h state in registers
    float hreg[2] = {0.f, 0.f};

    // x A-fragment source: M row mA -> batch row 2*(mA>>2) + (mA&1)
    // (rows with (mA&3)>=2 duplicate — their C rows are never consumed)
    const unsigned short* xsp = &xstage[0][2 * (mA >> 2) + (mA & 1)][0];

    // Ax register pipeline: Ax holds fragment for step t; AxN prefetches t+1.
    bfu Ax;
    {
        const unsigned* xp = (const unsigned*)xsp;
        Ax.u[0] = xp[0]; Ax.u[1] = xp[1]; Ax.u[2] = xp[2]; Ax.u[3] = 0u;
    }

    auto gru_step = [&](const unsigned short (*bufR)[ASTRIDE],
                        unsigned short (*bufW)[ASTRIDE], int T){
        const unsigned short* ah_ = &bufR[mA][0];
        bfrag Ah0 = *(const bfrag*)(ah_ + 0  + quad * 8);
        bfrag Ah1 = *(const bfrag*)(ah_ + 32 + quad * 8);
        const int tn_ = (T + 1) & (T_LEN - 1);
        const unsigned* xpn = (const unsigned*)(xsp + (size_t)tn_ * (ROWS * 6));
        bfu AxN;
        AxN.u[0] = xpn[0]; AxN.u[1] = xpn[1]; AxN.u[2] = xpn[2]; AxN.u[3] = 0u;
        // x-part first: Ax resident, overlaps Ah ds_read latency.
        // C-inputs are hoisted bias frags; results land in fresh accumulators.
        ffrag aR  = MFMA16(Ax.f, Br[2], FBR );
        ffrag aZ  = MFMA16(Ax.f, Bz[2], FBZ );
        ffrag aNX = MFMA16(Ax.f, Bnx,   FBNX);
        // h-part: K-halves in INDEPENDENT accumulators (shorter dep chain)
        ffrag aNH  = MFMA16(Ah0, Bnh[0], FBNH);
        aR         = MFMA16(Ah0, Br[0],  aR  );
        aZ         = MFMA16(Ah0, Bz[0],  aZ  );
        ffrag aRb  = MFMA16(Ah1, Br[1],  FZ  );
        ffrag aZb  = MFMA16(Ah1, Bz[1],  FZ  );
        ffrag aNHb = MFMA16(Ah1, Bnh[1], FZ  );
        #pragma unroll
        for (int r_ = 0; r_ < 2; ++r_){
            float rp = aR[r_]  + aRb[r_];
            float zp = aZ[r_]  + aZb[r_];
            float hp = aNH[r_] + aNHb[r_];
            float rg = RCPF(1.0f + EXP2F(-rp));
            float zg = RCPF(1.0f + EXP2F(-zp));
            float yy = aNX[r_] + rg * hp;
            float ng = 1.0f - 2.0f * RCPF(EXP2F(yy) + 1.0f);
            float hn = fmaf(zg, hreg[r_] - ng, ng);
            hreg[r_] = hn;
            bufW[quad * 4 + r_][j] = f2bf_cvt(hn);
        }
        Ax = AxN;
        __syncthreads();
    };

    // ================= encoder GRU: 512 steps, 1 barrier/step, NO global ops =====
    for (int t = 0; t < T_LEN; t += 2){
        gru_step(Abuf[0], Abuf[1], t);
        gru_step(Abuf[1], Abuf[0], t + 1);
    }

    // ---- publish final h (fp32, from registers): batch row = 2*quad+r ----
    #pragma unroll
    for (int r_ = 0; r_ < 2; ++r_) hfp[2 * quad + r_][j] = hreg[r_];
    __syncthreads();

    // ================= heads: mu, logvar, z0 =================
    const int zrow = tid >> 4, zi = tid & 15;
    float z0v = 0.0f;
    if (tid < ROWS * LAT){
        float am = mub[zi], al = lvb[zi];
        const float4* pm = (const float4*)(muW + (size_t)zi * HID);
        const float4* pq = (const float4*)(lvW + (size_t)zi * HID);
        const float4* ph = (const float4*)(&hfp[zrow][0]);
        #pragma unroll
        for (int q = 0; q < 16; ++q){
            float4 wm = pm[q], wl = pq[q], hv = ph[q];
            am += wm.x*hv.x + wm.y*hv.y + wm.z*hv.z + wm.w*hv.w;
            al += wl.x*hv.x + wl.y*hv.y + wl.z*hv.z + wl.w*hv.w;
        }
        const size_t muBase = (size_t)B_TOTAL * T_LEN;
        out[muBase + (size_t)(b0 + zrow) * LAT + zi] = am;
        out[muBase + (size_t)B_TOTAL * LAT + (size_t)(b0 + zrow) * LAT + zi] = al;
        z0v = am + __expf(0.5f * al);
    }

    // ================= ODE: RK4, 24 fixed steps on [0,1] =================
    if (tid < ROWS * LAT){
        float ows[16];
        {
            const float4* pw = (const float4*)(oW + (size_t)zi * LAT);
            #pragma unroll
            for (int q = 0; q < 4; ++q){
                float4 w = pw[q];
                ows[4*q+0] = w.x; ows[4*q+1] = w.y; ows[4*q+2] = w.z; ows[4*q+3] = w.w;
            }
        }
        const float obv = ob[zi];
        float z = z0v;
        const float hstep = 1.0f / 24.0f;
        for (int s = 0; s < 24; ++s){
            float y, k1, k2, k3, k4;
            y = z;
            { float acc = obv;
              #pragma unroll
              for (int jj = 0; jj < 16; ++jj){ float yj = __shfl(y, jj, 16); acc = fmaf(ows[jj], yj, acc); }
              k1 = fmaxf(acc, 0.0f); }
            y = z + 0.5f * hstep * k1;
            { float acc = obv;
              #pragma unroll
              for (int jj = 0; jj < 16; ++jj){ float yj = __shfl(y, jj, 16); acc = fmaf(ows[jj], yj, acc); }
              k2 = fmaxf(acc, 0.0f); }
            y = z + 0.5f * hstep * k2;
            { float acc = obv;
              #pragma unroll
              for (int jj = 0; jj < 16; ++jj){ float yj = __shfl(y, jj, 16); acc = fmaf(ows[jj], yj, acc); }
              k3 = fmaxf(acc, 0.0f); }
            y = z + hstep * k3;
            { float acc = obv;
              #pragma unroll
              for (int jj = 0; jj < 16; ++jj){ float yj = __shfl(y, jj, 16); acc = fmaf(ows[jj], yj, acc); }
              k4 = fmaxf(acc, 0.0f); }
            z += (hstep / 6.0f) * (k1 + 2.0f*k2 + 2.0f*k3 + k4);
        }
        zsh[zrow][zi] = z;
    }
    __syncthreads();

    // ================= decoder fc: zd = relu(z @ dfW.T + dfb) =================
    for (int idx = tid; idx < ROWS * HID; idx += THREADS){
        const int row = idx >> 6, o = idx & 63;
        float acc = dfb[o];
        const float4* pw = (const float4*)(dfW + (size_t)o * LAT);
        const float4* pz = (const float4*)(&zsh[row][0]);
        #pragma unroll
        for (int q = 0; q < 4; ++q){
            float4 w = pw[q], zv = pz[q];
            acc += w.x*zv.x + w.y*zv.y + w.z*zv.z + w.w*zv.w;
        }
        zdsh[row][o] = fmaxf(acc, 0.0f);
    }
    __syncthreads();

    // xg_dec = zd @ dec_Wih.T + dec_bih
    if (tid < ROWS * 3){
        const int row = tid / 3, gg = tid % 3;
        float acc = dbih[gg];
        const float4* pw = (const float4*)(dWih + (size_t)gg * HID);
        const float4* pz = (const float4*)(&zdsh[row][0]);
        #pragma unroll
        for (int q = 0; q < 16; ++q){
            float4 w = pw[q], zv = pz[q];
            acc += w.x*zv.x + w.y*zv.y + w.z*zv.z + w.w*zv.w;
        }
        xgdsh[row][gg] = acc;
    }
    __syncthreads();

    // ====== decoder GRU (hidden dim 1), 512 steps, direct float4 global stores ===
    if (tid < ROWS){
        const int row = tid;
        const float xr = xgdsh[row][0], xz = xgdsh[row][1], xn = xgdsh[row][2];
        const float A0 = dWhh[0], A1 = dWhh[1], A2 = dWhh[2];
        const float c0 = dbhh[0], c1 = dbhh[1], c2 = dbhh[2];
        float* orow = out + (size_t)(b0 + row) * T_LEN;   // 16B-aligned
        float h = 0.0f;
        float ob4[4];
        for (int t = 0; t < T_LEN; ++t){
            float rr = fast_sigmoid(xr + A0 * h + c0);
            float zz = fast_sigmoid(xz + A1 * h + c1);
            float nn = fast_tanh(xn + rr * (A2 * h + c2));
            h = (1.0f - zz) * nn + zz * h;
            ob4[t & 3] = h;
            if ((t & 3) == 3) *(float4*)(orow + (t - 3)) = *(float4*)ob4;
        }
    }
}

extern "C" void kernel_launch(void* const* d_in, const int* in_sizes, int n_in,
                              void* d_out, int out_size, void* d_ws, size_t ws_size,
                              hipStream_t stream){
    glsde_kernel<<<B_TOTAL / ROWS, THREADS, 0, stream>>>(
        (const float*)d_in[0],  (const float*)d_in[1],  (const float*)d_in[2],
        (const float*)d_in[3],  (const float*)d_in[4],  (const float*)d_in[5],
        (const float*)d_in[6],  (const float*)d_in[7],  (const float*)d_in[8],
        (const float*)d_in[9],  (const float*)d_in[10], (const float*)d_in[11],
        (const float*)d_in[12], (const float*)d_in[13], (const float*)d_in[14],
        (const float*)d_in[15], (const float*)d_in[16], (float*)d_out);
}

// Round 5
// 318.270 us; speedup vs baseline: 1.2290x; 1.0081x over previous
//
#include <hip/hip_runtime.h>
#include <math.h>

#define B_TOTAL 2048
#define T_LEN   512
#define IN_D    6
#define HID     64
#define LAT     16
#define ROWS    8          // batch rows per block; M rows {0,1,4,5,8,9,12,13}: quad q regs 0..1 = rows 2q,2q+1
#define THREADS 256        // 4 waves; wave w owns output units j in [16w,16w+16) for all 3 gates
#define ASTRIDE 104        // A row stride in bf16 elems (208B = 13x16B aligned)

typedef __attribute__((ext_vector_type(8))) short bfrag;   // 8 bf16 = 4 VGPRs
typedef __attribute__((ext_vector_type(4))) float ffrag;   // 4 fp32 acc
typedef union { bfrag f; unsigned u[4]; } bfu;

#if __has_builtin(__builtin_amdgcn_exp2f)
#define EXP2F(x) __builtin_amdgcn_exp2f(x)
#else
#define EXP2F(x) exp2f(x)
#endif
#if __has_builtin(__builtin_amdgcn_rcpf)
#define RCPF(x) __builtin_amdgcn_rcpf(x)
#else
#define RCPF(x) (1.0f / (x))
#endif
#define MFMA16(A, B, C) __builtin_amdgcn_mfma_f32_16x16x32_bf16((A), (B), (C), 0, 0, 0)

__device__ __forceinline__ float fast_sigmoid(float x){
    return RCPF(1.0f + EXP2F(-1.44269504088896340736f * x));
}
__device__ __forceinline__ float fast_tanh(float x){
    return 1.0f - 2.0f * RCPF(EXP2F(2.88539008177792681472f * x) + 1.0f);
}
// single-instruction bf16 round-to-nearest-even
__device__ __forceinline__ unsigned short f2bf_cvt(float f){
    unsigned r;
    asm("v_cvt_pk_bf16_f32 %0, %1, %1" : "=v"(r) : "v"(f));
    return (unsigned short)r;
}
// pack two f32 -> two bf16 in one dword (lo in [15:0], hi in [31:16])
__device__ __forceinline__ unsigned f2bf_pk(float lo, float hi){
    unsigned r;
    asm("v_cvt_pk_bf16_f32 %0, %1, %2" : "=v"(r) : "v"(lo), "v"(hi));
    return r;
}

extern "C" __global__ void
__attribute__((amdgpu_flat_work_group_size(THREADS, THREADS)))
glsde_kernel(const float* __restrict__ x,
             const float* __restrict__ eWih, const float* __restrict__ eWhh,
             const float* __restrict__ ebih, const float* __restrict__ ebhh,
             const float* __restrict__ muW,  const float* __restrict__ mub,
             const float* __restrict__ lvW,  const float* __restrict__ lvb,
             const float* __restrict__ oW,   const float* __restrict__ ob,
             const float* __restrict__ dfW,  const float* __restrict__ dfb,
             const float* __restrict__ dWih, const float* __restrict__ dWhh,
             const float* __restrict__ dbih, const float* __restrict__ dbhh,
             float* __restrict__ out)
{
    // x for this block, bf16, packed 6 shorts per (t,row): 48 KB.
    __shared__ __align__(16) unsigned short xstage[T_LEN][ROWS][6];
    __shared__ __align__(16) unsigned short Abuf[2][16][ASTRIDE];  // [buf][m][k] bf16 (h part)
    __shared__ float hfp[ROWS][HID];
    __shared__ float zsh[ROWS][LAT];
    __shared__ float zdsh[ROWS][HID];
    __shared__ float xgdsh[ROWS][3];

    const int tid  = threadIdx.x;
    const int wave = tid >> 6;
    const int lane = tid & 63;
    const int nloc = lane & 15;
    const int quad = lane >> 4;
    const int mA   = lane & 15;
    const int j    = wave * 16 + nloc;   // output unit 0..63
    const int b0   = blockIdx.x * ROWS;

    const float S1 = 1.44269504088896340736f;  // log2(e): sigmoid via exp2
    const float S2 = 2.0f * S1;                // tanh via exp2(2x)

    // ---- weights (pre-scaled by S1/S2) -> registers, plain bf16, loaded ONCE ----
    bfrag Br[3], Bz[3], Bnh[2], Bnx;
    {
        const float* wr  = eWhh + (size_t)(      j) * HID;
        const float* wz  = eWhh + (size_t)( 64 + j) * HID;
        const float* wn  = eWhh + (size_t)(128 + j) * HID;
        #pragma unroll
        for (int kt = 0; kt < 2; ++kt){
            const int o = kt * 32 + quad * 8;
            #pragma unroll
            for (int e = 0; e < 8; ++e){
                Br[kt][e]  = (short)f2bf_cvt(wr[o+e] * S1);
                Bz[kt][e]  = (short)f2bf_cvt(wz[o+e] * S1);
                Bnh[kt][e] = (short)f2bf_cvt(wn[o+e] * S2);
            }
        }
        const float* ir  = eWih + (size_t)(      j) * IN_D;
        const float* iz  = eWih + (size_t)( 64 + j) * IN_D;
        const float* inn = eWih + (size_t)(128 + j) * IN_D;
        #pragma unroll
        for (int e = 0; e < 8; ++e){
            bool v = (quad == 0 && e < IN_D);
            Br[2][e] = v ? (short)f2bf_cvt(ir[e]  * S1) : (short)0;
            Bz[2][e] = v ? (short)f2bf_cvt(iz[e]  * S1) : (short)0;
            Bnx[e]   = v ? (short)f2bf_cvt(inn[e] * S2) : (short)0;
        }
    }
    const float bias_r = (ebih[j]      + ebhh[j])      * S1;
    const float bias_z = (ebih[64 + j] + ebhh[64 + j]) * S1;
    const float bihn2  = ebih[128 + j] * S2;
    const float bhhn2  = ebhh[128 + j] * S2;

    // hoisted C-input fragments (loop-invariant)
    const ffrag FBR  = {bias_r, bias_r, bias_r, bias_r};
    const ffrag FBZ  = {bias_z, bias_z, bias_z, bias_z};
    const ffrag FBNX = {bihn2,  bihn2,  bihn2,  bihn2 };
    const ffrag FBNH = {bhhn2,  bhhn2,  bhhn2,  bhhn2 };
    const ffrag FZ   = {0.0f, 0.0f, 0.0f, 0.0f};

    // ---- zero Abuf (h(0)=0; M rows 4q+2,4q+3 stay 0 forever) ----
    {
        unsigned* ap = (unsigned*)Abuf;
        for (int i = tid; i < (int)(sizeof(Abuf) / 4); i += THREADS) ap[i] = 0u;
    }

    // ---- stage ALL of x for this block into LDS (one-time), bf16-packed ----
    for (int idx = tid; idx < T_LEN * ROWS; idx += THREADS){
        const int tt = idx & (T_LEN - 1);
        const int bb = idx >> 9;
        const float* xr = x + (size_t)(b0 + bb) * T_LEN * IN_D + (size_t)tt * IN_D;
        const float2* p2 = (const float2*)xr;           // 8B-aligned (24B stride)
        float2 v0 = p2[0], v1 = p2[1], v2 = p2[2];
        unsigned* dst = (unsigned*)&xstage[tt][bb][0];  // 12B-aligned -> dword ok
        dst[0] = f2bf_pk(v0.x, v0.y);
        dst[1] = f2bf_pk(v1.x, v1.y);
        dst[2] = f2bf_pk(v2.x, v2.y);
    }
    __syncthreads();

    // lane (quad, reg r<2) owns batch row 2*quad+r; h state in registers
    float hreg[2] = {0.f, 0.f};

    // x A-fragment source: M row mA -> batch row 2*(mA>>2) + (mA&1)
    // (rows with (mA&3)>=2 duplicate — their C rows are never consumed)
    const unsigned short* xsp = &xstage[0][2 * (mA >> 2) + (mA & 1)][0];

    // Ax register pipeline: Ax holds fragment for step t; AxN prefetches t+1.
    bfu Ax;
    {
        const unsigned* xp = (const unsigned*)xsp;
        Ax.u[0] = xp[0]; Ax.u[1] = xp[1]; Ax.u[2] = xp[2]; Ax.u[3] = 0u;
    }

    auto gru_step = [&](const unsigned short (*bufR)[ASTRIDE],
                        unsigned short (*bufW)[ASTRIDE], int T){
        const unsigned short* ah_ = &bufR[mA][0];
        bfrag Ah0 = *(const bfrag*)(ah_ + 0  + quad * 8);
        bfrag Ah1 = *(const bfrag*)(ah_ + 32 + quad * 8);
        const int tn_ = (T + 1) & (T_LEN - 1);
        const unsigned* xpn = (const unsigned*)(xsp + (size_t)tn_ * (ROWS * 6));
        bfu AxN;
        AxN.u[0] = xpn[0]; AxN.u[1] = xpn[1]; AxN.u[2] = xpn[2]; AxN.u[3] = 0u;
        // x-part first: Ax resident, overlaps Ah ds_read latency.
        ffrag aR  = MFMA16(Ax.f, Br[2], FBR );
        ffrag aZ  = MFMA16(Ax.f, Bz[2], FBZ );
        ffrag aNX = MFMA16(Ax.f, Bnx,   FBNX);
        // h-part: K-halves in INDEPENDENT accumulators (shorter dep chain)
        ffrag aNH  = MFMA16(Ah0, Bnh[0], FBNH);
        aR         = MFMA16(Ah0, Br[0],  aR  );
        aZ         = MFMA16(Ah0, Bz[0],  aZ  );
        ffrag aRb  = MFMA16(Ah1, Br[1],  FZ  );
        ffrag aZb  = MFMA16(Ah1, Bz[1],  FZ  );
        ffrag aNHb = MFMA16(Ah1, Bnh[1], FZ  );
        #pragma unroll
        for (int r_ = 0; r_ < 2; ++r_){
            const float h  = hreg[r_];
            const float rp = aR[r_]  + aRb[r_];
            const float zp = aZ[r_]  + aZb[r_];
            const float hp = aNH[r_] + aNHb[r_];
            // sigmoid(r): rg = 1/(1+2^-rp)
            const float Er = EXP2F(-rp);
            const float rg = RCPF(1.0f + Er);
            const float yy = fmaf(rg, hp, aNX[r_]);
            // merged tanh+blend: hn = [Ez(En-1) + h(En+1)] / [(En+1)(Ez+1)]
            const float En = EXP2F(yy);
            const float Ez = EXP2F(-zp);
            const float t1 = En - 1.0f;
            const float t2 = En + 1.0f;
            const float num = fmaf(Ez, t1, h * t2);
            const float den = t2 * (Ez + 1.0f);
            const float hn  = num * RCPF(den);
            hreg[r_] = hn;
            bufW[quad * 4 + r_][j] = f2bf_cvt(hn);
        }
        Ax = AxN;
        __syncthreads();
    };

    // ================= encoder GRU: 512 steps, 1 barrier/step, NO global ops =====
    for (int t = 0; t < T_LEN; t += 2){
        gru_step(Abuf[0], Abuf[1], t);
        gru_step(Abuf[1], Abuf[0], t + 1);
    }

    // ---- publish final h (fp32, from registers): batch row = 2*quad+r ----
    #pragma unroll
    for (int r_ = 0; r_ < 2; ++r_) hfp[2 * quad + r_][j] = hreg[r_];
    __syncthreads();

    // ================= heads: mu, logvar, z0 =================
    const int zrow = tid >> 4, zi = tid & 15;
    float z0v = 0.0f;
    if (tid < ROWS * LAT){
        float am = mub[zi], al = lvb[zi];
        const float4* pm = (const float4*)(muW + (size_t)zi * HID);
        const float4* pq = (const float4*)(lvW + (size_t)zi * HID);
        const float4* ph = (const float4*)(&hfp[zrow][0]);
        #pragma unroll
        for (int q = 0; q < 16; ++q){
            float4 wm = pm[q], wl = pq[q], hv = ph[q];
            am += wm.x*hv.x + wm.y*hv.y + wm.z*hv.z + wm.w*hv.w;
            al += wl.x*hv.x + wl.y*hv.y + wl.z*hv.z + wl.w*hv.w;
        }
        const size_t muBase = (size_t)B_TOTAL * T_LEN;
        out[muBase + (size_t)(b0 + zrow) * LAT + zi] = am;
        out[muBase + (size_t)B_TOTAL * LAT + (size_t)(b0 + zrow) * LAT + zi] = al;
        z0v = am + __expf(0.5f * al);
    }

    // ================= ODE: RK4, 24 fixed steps on [0,1] =================
    if (tid < ROWS * LAT){
        float ows[16];
        {
            const float4* pw = (const float4*)(oW + (size_t)zi * LAT);
            #pragma unroll
            for (int q = 0; q < 4; ++q){
                float4 w = pw[q];
                ows[4*q+0] = w.x; ows[4*q+1] = w.y; ows[4*q+2] = w.z; ows[4*q+3] = w.w;
            }
        }
        const float obv = ob[zi];
        float z = z0v;
        const float hstep = 1.0f / 24.0f;
        for (int s = 0; s < 24; ++s){
            float y, k1, k2, k3, k4;
            y = z;
            { float a0 = obv, a1 = 0.0f;
              #pragma unroll
              for (int jj = 0; jj < 8; ++jj){
                  float y0 = __shfl(y, jj, 16), y1 = __shfl(y, jj + 8, 16);
                  a0 = fmaf(ows[jj], y0, a0); a1 = fmaf(ows[jj + 8], y1, a1);
              }
              k1 = fmaxf(a0 + a1, 0.0f); }
            y = z + 0.5f * hstep * k1;
            { float a0 = obv, a1 = 0.0f;
              #pragma unroll
              for (int jj = 0; jj < 8; ++jj){
                  float y0 = __shfl(y, jj, 16), y1 = __shfl(y, jj + 8, 16);
                  a0 = fmaf(ows[jj], y0, a0); a1 = fmaf(ows[jj + 8], y1, a1);
              }
              k2 = fmaxf(a0 + a1, 0.0f); }
            y = z + 0.5f * hstep * k2;
            { float a0 = obv, a1 = 0.0f;
              #pragma unroll
              for (int jj = 0; jj < 8; ++jj){
                  float y0 = __shfl(y, jj, 16), y1 = __shfl(y, jj + 8, 16);
                  a0 = fmaf(ows[jj], y0, a0); a1 = fmaf(ows[jj + 8], y1, a1);
              }
              k3 = fmaxf(a0 + a1, 0.0f); }
            y = z + hstep * k3;
            { float a0 = obv, a1 = 0.0f;
              #pragma unroll
              for (int jj = 0; jj < 8; ++jj){
                  float y0 = __shfl(y, jj, 16), y1 = __shfl(y, jj + 8, 16);
                  a0 = fmaf(ows[jj], y0, a0); a1 = fmaf(ows[jj + 8], y1, a1);
              }
              k4 = fmaxf(a0 + a1, 0.0f); }
            z += (hstep / 6.0f) * (k1 + 2.0f*k2 + 2.0f*k3 + k4);
        }
        zsh[zrow][zi] = z;
    }
    __syncthreads();

    // ================= decoder fc: zd = relu(z @ dfW.T + dfb) =================
    for (int idx = tid; idx < ROWS * HID; idx += THREADS){
        const int row = idx >> 6, o = idx & 63;
        float acc = dfb[o];
        const float4* pw = (const float4*)(dfW + (size_t)o * LAT);
        const float4* pz = (const float4*)(&zsh[row][0]);
        #pragma unroll
        for (int q = 0; q < 4; ++q){
            float4 w = pw[q], zv = pz[q];
            acc += w.x*zv.x + w.y*zv.y + w.z*zv.z + w.w*zv.w;
        }
        zdsh[row][o] = fmaxf(acc, 0.0f);
    }
    __syncthreads();

    // xg_dec = zd @ dec_Wih.T + dec_bih
    if (tid < ROWS * 3){
        const int row = tid / 3, gg = tid % 3;
        float acc = dbih[gg];
        const float4* pw = (const float4*)(dWih + (size_t)gg * HID);
        const float4* pz = (const float4*)(&zdsh[row][0]);
        #pragma unroll
        for (int q = 0; q < 16; ++q){
            float4 w = pw[q], zv = pz[q];
            acc += w.x*zv.x + w.y*zv.y + w.z*zv.z + w.w*zv.w;
        }
        xgdsh[row][gg] = acc;
    }
    __syncthreads();

    // ====== decoder GRU (hidden dim 1), 512 steps, fixed-point early exit =======
    // Constant input per row -> h_{t+1} = G(h_t) is a fixed 1-D map. Once
    // h_new == h_old BITWISE, every later value is identical -> fill with h*.
    if (tid < ROWS){
        const int row = tid;
        const float xn = xgdsh[row][2];
        const float A0 = dWhh[0], A1 = dWhh[1], A2 = dWhh[2];
        const float c2 = dbhh[2];
        const float K0 = xgdsh[row][0] + dbhh[0];   // xr + c0 folded
        const float K1 = xgdsh[row][1] + dbhh[1];   // xz + c1 folded
        float* orow = out + (size_t)(b0 + row) * T_LEN;   // 16B-aligned
        float h = 0.0f;
        float ob4[4];
        int t = 0;
        for (; t < T_LEN; ++t){
            const float hp = h;
            float rr = fast_sigmoid(fmaf(A0, h, K0));
            float zz = fast_sigmoid(fmaf(A1, h, K1));
            float nn = fast_tanh(fmaf(rr, fmaf(A2, h, c2), xn));
            h = fmaf(zz, hp - nn, nn);
            ob4[t & 3] = h;
            if ((t & 3) == 3) *(float4*)(orow + (t - 3)) = *(float4*)ob4;
            if (h == hp){ ++t; break; }   // exact fixed point reached
        }
        // finish partial quad with h*
        for (; t < T_LEN && (t & 3) != 0; ++t){
            ob4[t & 3] = h;
            if ((t & 3) == 3) *(float4*)(orow + (t - 3)) = *(float4*)ob4;
        }
        // bulk fill with h*
        float4 hv; hv.x = h; hv.y = h; hv.z = h; hv.w = h;
        for (; t < T_LEN; t += 4) *(float4*)(orow + t) = hv;
    }
}

extern "C" void kernel_launch(void* const* d_in, const int* in_sizes, int n_in,
                              void* d_out, int out_size, void* d_ws, size_t ws_size,
                              hipStream_t stream){
    glsde_kernel<<<B_TOTAL / ROWS, THREADS, 0, stream>>>(
        (const float*)d_in[0],  (const float*)d_in[1],  (const float*)d_in[2],
        (const float*)d_in[3],  (const float*)d_in[4],  (const float*)d_in[5],
        (const float*)d_in[6],  (const float*)d_in[7],  (const float*)d_in[8],
        (const float*)d_in[9],  (const float*)d_in[10], (const float*)d_in[11],
        (const float*)d_in[12], (const float*)d_in[13], (const float*)d_in[14],
        (const float*)d_in[15], (const float*)d_in[16], (float*)d_out);
}